// Round 1
// baseline (85.468 us; speedup 1.0000x reference)
//
#include <hip/hip_runtime.h>

// FlexChannelPConv2D — MI355X fp32 implementation.
//
// Key facts derived from the static build (C_IN=8, H=W=40, B=4, ksize=5):
//   F = 9 basis fns: rings (R,sigma) = (0,.6),(1,.6),(2,.4), freqs bandlimited.
//   pre_cut keeps f>=0 entries: per channel 6 kept basis fns, order
//   (ring0,f0),(ring1,f0),(ring1,f1),(ring2,f0),(ring2,f1),(ring2,f2).
//   FSEL=48 rows, COUT=36 cols, NNZ=576 (cols have 24/16/8 rows).
//   pre_mul is all-ones for this config but we apply it from the input anyway.
//
// Locality: envelope exp(-((r-R)/(sqrt2*sigma))^2) < 2e-10 for r>=5, so only
// |dy|<=4, |dx|<=4 neighbors contribute (error ~1e-6 << 8e-2 threshold).
// Angular factors: cos(a)=dx/r, sin(a)=dy/r, double-angle for f=2 — no trig.
// All filter primitives depend only on the integer offset -> 81-entry LDS table.

#define HGRID 40
#define WGRID 40
#define NP    1600
#define NB    4
#define NC    8
#define COUT  36
#define NNZ   576
#define FSEL  48
#define WIN   4
#define WTAB  9
#define MAXROW 24

__global__ __launch_bounds__(512)
void flexpconv_kernel(const float* __restrict__ data,      // [4][1600][8]
                      const float* __restrict__ weights,   // [576][2]
                      const float* __restrict__ brad,      // [9]
                      const float* __restrict__ bsig,      // [9]
                      const float* __restrict__ premul,    // [48][2]
                      const int*   __restrict__ conn_rows, // [576]
                      const int*   __restrict__ conn_cols, // [576]
                      const int*   __restrict__ out_rot,   // [36]
                      float*       __restrict__ out)       // [4][1600][36][2]
{
    __shared__ float tab[WTAB * WTAB][8];   // E0,E1,E2,c1,s1,c2,s2,pad per offset
    __shared__ float ppbuf[8][FSEL][2];     // per-q selected pp (premul applied)
    __shared__ int   colRow[MAXROW][COUT];
    __shared__ float colWre[MAXROW][COUT];
    __shared__ float colWim[MAXROW][COUT];
    __shared__ int   colCnt[COUT];

    const int tid = threadIdx.x;

    // ---- phase 0: offset table + zero col counters (before barrier 1) ----
    if (tid < COUT) colCnt[tid] = 0;
    if (tid < WTAB * WTAB) {
        const int dy = tid / WTAB - WIN;
        const int dx = tid % WTAB - WIN;
        const float fy = (float)dy, fx = (float)dx;
        const float r2 = fy * fy + fx * fx;
        const float r  = sqrtf(r2);
        const float inv_s2 = 0.70710678118654752f; // 1/sqrt(2)
        // ring params live at basis indices 0,1,4 (ring-major basis layout)
        const float R0 = brad[0], S0 = bsig[0];
        const float R1 = brad[1], S1 = bsig[1];
        const float R2 = brad[4], S2 = bsig[4];
        float t0 = (r - R0) * inv_s2 / S0;
        float t1 = (r - R1) * inv_s2 / S1;
        float t2 = (r - R2) * inv_s2 / S2;
        float e0 = expf(-t0 * t0);
        float e1 = expf(-t1 * t1);
        float e2 = expf(-t2 * t2);
        float c1 = 0.f, s1 = 0.f, c2v = 0.f, s2v = 0.f;
        if (r2 > 0.f) {               // r==0: mask kills f!=0 terms -> c/s = 0
            const float ir = 1.f / r;
            c1 = fx * ir;             // cos(atan2(dy,dx))
            s1 = fy * ir;             // sin(atan2(dy,dx))
            c2v = c1 * c1 - s1 * s1;  // cos(2a)
            s2v = 2.f * c1 * s1;      // sin(2a)
        }
        tab[tid][0] = e0; tab[tid][1] = e1; tab[tid][2] = e2; tab[tid][3] = c1;
        tab[tid][4] = s1; tab[tid][5] = c2v; tab[tid][6] = s2v; tab[tid][7] = 0.f;
    }
    __syncthreads();

    // ---- phase 0b: scatter sparse weights into per-column lists ----
    for (int n = tid; n < NNZ; n += 512) {
        const int col  = conn_cols[n];
        const int slot = atomicAdd(&colCnt[col], 1);
        colRow[slot][col] = conn_rows[n];
        colWre[slot][col] = weights[2 * n];
        colWim[slot][col] = weights[2 * n + 1];
    }

    // ---- phase 1: windowed accumulation ----
    // thread = (ql[3b] | half[1b] | b[2b] | c[3b]); one wave per q (halves are
    // lanes 0-31 vs 32-63 -> shfl_xor(32) reduction).
    const int c    = tid & 7;
    const int b    = (tid >> 3) & 3;
    const int half = (tid >> 5) & 1;
    const int ql   = tid >> 6;                 // 0..7
    const int q    = blockIdx.x * 8 + ql;
    const int qy   = q / WGRID;
    const int qx   = q - qy * WGRID;

    // kept basis order per channel: (r0,f0) (r1,f0) (r1,f1) (r2,f0) (r2,f1) (r2,f2)
    float p0 = 0.f, p1 = 0.f, p3 = 0.f;              // f=0 -> purely real
    float p2r = 0.f, p2i = 0.f;                      // ring1 f=1
    float p4r = 0.f, p4i = 0.f;                      // ring2 f=1
    float p5r = 0.f, p5i = 0.f;                      // ring2 f=2

    const int dy_lo = half ? 1 : -WIN;
    const int dy_hi = half ? WIN : 0;
    for (int dy = dy_lo; dy <= dy_hi; ++dy) {
        const int py = qy + dy;
        if (py < 0 || py >= HGRID) continue;
        const int rowbase = (b * NP + py * WGRID) * NC + c;
        const int obase   = (dy + WIN) * WTAB;
        #pragma unroll
        for (int dx = -WIN; dx <= WIN; ++dx) {
            const int px = qx + dx;
            if (px < 0 || px >= WGRID) continue;
            const float4 tA = *(const float4*)&tab[obase + dx + WIN][0];
            const float4 tB = *(const float4*)&tab[obase + dx + WIN][4];
            const float d = data[rowbase + px * NC];
            p0 += d * tA.x;                       // E0
            p1 += d * tA.y;                       // E1
            p3 += d * tA.z;                       // E2
            const float dc1 = d * tA.w, ds1 = d * tB.x;
            const float dc2 = d * tB.y, ds2 = d * tB.z;
            p2r += dc1 * tA.y; p2i += ds1 * tA.y;
            p4r += dc1 * tA.z; p4i += ds1 * tA.z;
            p5r += dc2 * tA.z; p5i += ds2 * tA.z;
        }
    }

    // reduce the two window halves (lanes 0-31 <-> 32-63 of the same wave)
    p0  += __shfl_xor(p0, 32);  p1  += __shfl_xor(p1, 32);
    p3  += __shfl_xor(p3, 32);
    p2r += __shfl_xor(p2r, 32); p2i += __shfl_xor(p2i, 32);
    p4r += __shfl_xor(p4r, 32); p4i += __shfl_xor(p4i, 32);
    p5r += __shfl_xor(p5r, 32); p5i += __shfl_xor(p5i, 32);

    if (half == 0) {
        // ppbuf holds pp for one q: but rows are (b,c)-specific... row index is
        // k = c*6+jj within a fixed b; store per-b planes interleaved via ql? No:
        // ppbuf is per (q, row) with b folded by using 4 sub-planes is wrong.
        // -> index by (ql, b handled in epilogue): store per (ql) only works if
        //    epilogue re-reads per b. We store per (ql, k) for OUR b by packing
        //    b into the row dimension is not possible (FSEL=48 covers c,f only).
        // Resolution: ppbuf must be per (ql, b): use 4x the rows.
        const int kb = c * 6;
        float* dst = &ppbuf[ql][0][0];     // overwritten below with b offset
        (void)dst;
        // store with b folded: row index = k, plane = b -> ppbuf[ql][k][...]
        // needs [8][4][48][2]; see union trick below.
    }
    // --- b-aware pp staging (FSEL rows x NB planes) ---
    __shared__ float ppb[8][NB][FSEL][2];  // 8*4*48*2*4B = 12 KiB
    if (half == 0) {
        const int kb = c * 6;
        ppb[ql][b][kb + 0][0] = p0  * premul[(kb + 0) * 2];
        ppb[ql][b][kb + 0][1] = 0.f;
        ppb[ql][b][kb + 1][0] = p1  * premul[(kb + 1) * 2];
        ppb[ql][b][kb + 1][1] = 0.f;
        ppb[ql][b][kb + 2][0] = p2r * premul[(kb + 2) * 2];
        ppb[ql][b][kb + 2][1] = p2i * premul[(kb + 2) * 2 + 1];
        ppb[ql][b][kb + 3][0] = p3  * premul[(kb + 3) * 2];
        ppb[ql][b][kb + 3][1] = 0.f;
        ppb[ql][b][kb + 4][0] = p4r * premul[(kb + 4) * 2];
        ppb[ql][b][kb + 4][1] = p4i * premul[(kb + 4) * 2 + 1];
        ppb[ql][b][kb + 5][0] = p5r * premul[(kb + 5) * 2];
        ppb[ql][b][kb + 5][1] = p5i * premul[(kb + 5) * 2 + 1];
    }
    __syncthreads();

    // ---- phase 2: apply sparse complex weights ----
    // epilogue thread = (ql, eb[2b], l16[4b]); covers co = l16, l16+16, l16+32
    const int r_  = tid & 63;
    const int eb  = r_ >> 4;     // batch 0..3
    const int l16 = r_ & 15;
    #pragma unroll
    for (int cc = 0; cc < 3; ++cc) {
        const int co = cc * 16 + l16;
        if (co >= COUT) continue;
        const int cnt = colCnt[co];
        float are = 0.f, aim = 0.f;
        for (int i = 0; i < cnt; ++i) {
            const int k  = colRow[i][co];
            const float wr = colWre[i][co];
            const float wi = colWim[i][co];
            const float pr = ppb[ql][eb][k][0];
            const float pi = ppb[ql][eb][k][1];
            are += pr * wr - pi * wi;
            aim += pr * wi + pi * wr;
        }
        if (out_rot[co] == 0) aim = 0.f;   // keep_imag mask
        const int oidx = ((eb * NP + q) * COUT + co) * 2;
        out[oidx]     = are;
        out[oidx + 1] = aim;
    }
}

extern "C" void kernel_launch(void* const* d_in, const int* in_sizes, int n_in,
                              void* d_out, int out_size, void* d_ws, size_t ws_size,
                              hipStream_t stream) {
    const float* data      = (const float*)d_in[0];
    // d_in[1] = inp_grid (implicit: unit-spacing integer grid)
    const float* weights   = (const float*)d_in[2];
    const float* brad      = (const float*)d_in[3];
    const float* bsig      = (const float*)d_in[4];
    // d_in[5] = basis_frequency (implicit in kept-basis structure)
    const float* premul    = (const float*)d_in[6];
    // d_in[7] = pre_cut_idx (implicit: kept order is c-major, basis-ascending)
    const int*   conn_rows = (const int*)d_in[8];
    const int*   conn_cols = (const int*)d_in[9];
    const int*   out_rot   = (const int*)d_in[10];
    float* out = (float*)d_out;

    flexpconv_kernel<<<NP / 8, 512, 0, stream>>>(
        data, weights, brad, bsig, premul, conn_rows, conn_cols, out_rot, out);
}